// Round 1
// baseline (2342.814 us; speedup 1.0000x reference)
//
#include <hip/hip_runtime.h>

// Problem constants
#define B_  4096
#define T_  64
#define D_  256
#define E_  128
#define H_  256
#define G_  1024   // 4*H
#define KS_ 384    // E + H

typedef __attribute__((ext_vector_type(8))) short short8;
typedef __attribute__((ext_vector_type(4))) float f32x4;

__device__ inline unsigned short f2bf(float f){
  unsigned u = __float_as_uint(f);
  u += 0x7FFFu + ((u >> 16) & 1u);   // RNE
  return (unsigned short)(u >> 16);
}
__device__ inline float sigm_(float x){ return 1.f/(1.f + __expf(-x)); }
__device__ inline float tanh_(float x){
  float xc = fminf(fmaxf(x, -15.f), 15.f);
  float e = __expf(2.f*xc);
  return (e - 1.f)/(e + 1.f);
}

// ---------------------------------------------------------------------------
// init: zero h0/c0, build Wcat = bf16([W_ih | W_hh]) [1024][384], biasc = b_ih+b_hh
// grid 4096 x 256  (covers 1,048,576 = B*H)
// ---------------------------------------------------------------------------
__global__ __launch_bounds__(256) void init_kernel(
    const float* __restrict__ W_ih, const float* __restrict__ b_ih,
    const float* __restrict__ W_hh, const float* __restrict__ b_hh,
    unsigned short* __restrict__ Wcat, float* __restrict__ biasc,
    unsigned short* __restrict__ h0, float* __restrict__ c0){
  int i = blockIdx.x*256 + threadIdx.x;
  h0[i] = 0;
  c0[i] = 0.f;
  if (i < G_*KS_){
    int g = i / KS_, k = i - g*KS_;
    float v = (k < E_) ? W_ih[g*E_ + k] : W_hh[g*H_ + (k - E_)];
    Wcat[i] = f2bf(v);
  }
  if (i < G_) biasc[i] = b_ih[i] + b_hh[i];
}

// ---------------------------------------------------------------------------
// enc = bf16(tanh(x @ W_enc^T + b_enc))  [B*T][E], MFMA 16x16x32 bf16
// block tile 128(M) x 128(N=E), BK=64, 4 waves each 32x128. grid 2048.
// ---------------------------------------------------------------------------
__global__ __launch_bounds__(256) void enc_kernel(
    const float* __restrict__ x, const float* __restrict__ W_enc,
    const float* __restrict__ b_enc, unsigned short* __restrict__ enc){
  __shared__ unsigned short As[128*64];   // swizzled, row stride 128B
  __shared__ unsigned short Bs[128*64];
  __shared__ float bes[128];
  const int tid = threadIdx.x;
  const int lane = tid & 63, w = tid >> 6;
  const int l15 = lane & 15, lq = lane >> 4;
  const int m0 = blockIdx.x * 128;
  if (tid < 128) bes[tid] = b_enc[tid];

  f32x4 acc[16];
  #pragma unroll
  for (int i=0;i<16;i++) acc[i] = (f32x4)0.f;

  for (int kc = 0; kc < 4; ++kc){
    const int kb = kc*64;
    __syncthreads();
    // stage A = x[m0..m0+127][kb..kb+63] fp32 -> bf16 (swizzled)
    #pragma unroll
    for (int i=0;i<4;i++){
      int u = i*256 + tid; int r = u>>3, s = u&7;
      const float* sp = x + (size_t)(m0+r)*D_ + kb + s*8;
      float4 v0 = *(const float4*)sp;
      float4 v1 = *(const float4*)(sp+4);
      short8 pk;
      pk[0]=(short)f2bf(v0.x); pk[1]=(short)f2bf(v0.y); pk[2]=(short)f2bf(v0.z); pk[3]=(short)f2bf(v0.w);
      pk[4]=(short)f2bf(v1.x); pk[5]=(short)f2bf(v1.y); pk[6]=(short)f2bf(v1.z); pk[7]=(short)f2bf(v1.w);
      int off = (r*128 + s*16) ^ ((r&7)<<4);
      *(short8*)((char*)As + off) = pk;
    }
    // stage B = W_enc[0..127][kb..kb+63]
    #pragma unroll
    for (int i=0;i<4;i++){
      int u = i*256 + tid; int r = u>>3, s = u&7;
      const float* sp = W_enc + (size_t)r*D_ + kb + s*8;
      float4 v0 = *(const float4*)sp;
      float4 v1 = *(const float4*)(sp+4);
      short8 pk;
      pk[0]=(short)f2bf(v0.x); pk[1]=(short)f2bf(v0.y); pk[2]=(short)f2bf(v0.z); pk[3]=(short)f2bf(v0.w);
      pk[4]=(short)f2bf(v1.x); pk[5]=(short)f2bf(v1.y); pk[6]=(short)f2bf(v1.z); pk[7]=(short)f2bf(v1.w);
      int off = (r*128 + s*16) ^ ((r&7)<<4);
      *(short8*)((char*)Bs + off) = pk;
    }
    __syncthreads();
    #pragma unroll
    for (int kk=0;kk<2;kk++){
      short8 af[2];
      #pragma unroll
      for (int mi=0;mi<2;mi++){
        int r = 32*w + mi*16 + l15;
        int off = (r*128 + kk*64 + lq*16) ^ ((r&7)<<4);
        af[mi] = *(const short8*)((const char*)As + off);
      }
      #pragma unroll
      for (int nf=0;nf<8;nf++){
        int r = nf*16 + l15;
        int off = (r*128 + kk*64 + lq*16) ^ ((r&7)<<4);
        short8 bfr = *(const short8*)((const char*)Bs + off);
        #pragma unroll
        for (int mi=0;mi<2;mi++)
          acc[mi*8+nf] = __builtin_amdgcn_mfma_f32_16x16x32_bf16(af[mi], bfr, acc[mi*8+nf], 0,0,0);
      }
    }
  }
  // epilogue: tanh + bias, store bf16
  #pragma unroll
  for (int mi=0;mi<2;mi++){
    #pragma unroll
    for (int nf=0;nf<8;nf++){
      int col = nf*16 + l15;
      float be = bes[col];
      #pragma unroll
      for (int j=0;j<4;j++){
        int row = m0 + 32*w + mi*16 + lq*4 + j;
        enc[(size_t)row*E_ + col] = f2bf(tanh_(acc[mi*8+nf][j] + be));
      }
    }
  }
}

// ---------------------------------------------------------------------------
// one LSTM step: gates = [enc_t | h] @ Wcat^T + bias; pointwise update;
// writes h_out (bf16), c (fp32), abs-diff into loss_dim_t (t<63) or h_n (t=63).
// block tile 64(M rows of B) x 256(gate cols: 64 h x 4 gates), BK=64, K=384.
// 4 waves, each 16x256 -> all 4 gates of a (b,h) cell live in the same lane/reg.
// grid (64, 4): y = h-chunk of 64.
// ---------------------------------------------------------------------------
__global__ __launch_bounds__(256) void step_kernel(
    const unsigned short* __restrict__ enc,
    const unsigned short* __restrict__ Wcat,
    const float* __restrict__ biasc,
    const unsigned short* __restrict__ h_in,
    unsigned short* __restrict__ h_out,
    float* __restrict__ c,
    const float* __restrict__ x,
    float* __restrict__ out_hn,
    float* __restrict__ out_ldt,
    int t){
  __shared__ unsigned short As[64*64];    // 8 KB
  __shared__ unsigned short Bs[256*64];   // 32 KB
  __shared__ float bss[256];
  const int tid = threadIdx.x;
  const int lane = tid & 63, w = tid >> 6;
  const int l15 = lane & 15, lq = lane >> 4;
  const int m0 = blockIdx.x * 64;
  const int gh0 = blockIdx.y * 64;
  bss[tid] = biasc[(tid>>6)*H_ + gh0 + (tid&63)];

  f32x4 acc[16];
  #pragma unroll
  for (int i=0;i<16;i++) acc[i] = (f32x4)0.f;

  for (int kc=0; kc<6; ++kc){
    const int kb = kc*64;
    __syncthreads();
    // A tile 64x64: rows = batch rows, cols kb..kb+63 of [enc_t | h]
    #pragma unroll
    for (int i=0;i<2;i++){
      int u = i*256 + tid; int r = u>>3, s = u&7;
      const unsigned short* sp;
      if (kb < E_) sp = enc + ((size_t)(m0+r)*T_ + t)*E_ + kb + s*8;
      else         sp = h_in + (size_t)(m0+r)*H_ + (kb - E_) + s*8;
      short8 v = *(const short8*)sp;
      int off = (r*128 + s*16) ^ ((r&7)<<4);
      *(short8*)((char*)As + off) = v;
    }
    // B tile 256x64: tile row r -> Wcat row (r>>6)*256 + gh0 + (r&63)
    #pragma unroll
    for (int i=0;i<8;i++){
      int u = i*256 + tid; int r = u>>3, s = u&7;
      int gr = (r>>6)*H_ + gh0 + (r&63);
      const unsigned short* sp = Wcat + (size_t)gr*KS_ + kb + s*8;
      short8 v = *(const short8*)sp;
      int off = (r*128 + s*16) ^ ((r&7)<<4);
      *(short8*)((char*)Bs + off) = v;
    }
    __syncthreads();
    #pragma unroll
    for (int kk=0;kk<2;kk++){
      int ra = 16*w + l15;
      int offa = (ra*128 + kk*64 + lq*16) ^ ((ra&7)<<4);
      short8 af = *(const short8*)((const char*)As + offa);
      #pragma unroll
      for (int nf=0;nf<16;nf++){
        int rb = nf*16 + l15;
        int offb = (rb*128 + kk*64 + lq*16) ^ ((rb&7)<<4);
        short8 bfr = *(const short8*)((const char*)Bs + offb);
        acc[nf] = __builtin_amdgcn_mfma_f32_16x16x32_bf16(af, bfr, acc[nf], 0,0,0);
      }
    }
  }
  // pointwise LSTM update; gate q of cell lives in acc[q*4+cf][j]
  #pragma unroll
  for (int cf=0; cf<4; ++cf){
    float bi  = bss[      cf*16 + l15];
    float bfg = bss[ 64 + cf*16 + l15];
    float bg  = bss[128 + cf*16 + l15];
    float bo  = bss[192 + cf*16 + l15];
    #pragma unroll
    for (int j=0;j<4;j++){
      int b = m0 + 16*w + lq*4 + j;
      int h = gh0 + cf*16 + l15;
      size_t idx = (size_t)b*H_ + h;
      float gi = sigm_(acc[cf][j]    + bi);
      float gf = sigm_(acc[4+cf][j]  + bfg);
      float gg = tanh_(acc[8+cf][j]  + bg);
      float go = sigm_(acc[12+cf][j] + bo);
      float cn = gf * c[idx] + gi * gg;
      c[idx] = cn;
      float hn = go * tanh_(cn);
      h_out[idx] = f2bf(hn);
      if (t < T_-1){
        float xv = x[((size_t)b*T_ + (t+1))*D_ + h];
        out_ldt[((size_t)b*T_ + t)*H_ + h] = fabsf(hn - xv);
      } else {
        out_hn[idx] = hn;
      }
    }
  }
}

// ---------------------------------------------------------------------------
// finalize: loss[b] = sum_t sqrt(sum_h ad^2)/63 ; loss_dim = sum_t ad/63 ;
// zero the t=T-1 slice of loss_dim_t. One wave per batch row. grid 1024.
// ---------------------------------------------------------------------------
__global__ __launch_bounds__(256) void final_kernel(
    float* __restrict__ out_loss, float* __restrict__ out_ldim,
    float* __restrict__ out_ldt){
  const int w = threadIdx.x >> 6, lane = threadIdx.x & 63;
  const int b = blockIdx.x*4 + w;
  const float* base = out_ldt + (size_t)b*(T_*H_);
  float adx=0.f, ady=0.f, adz=0.f, adw=0.f;
  float lacc = 0.f;
  for (int t=0;t<T_-1;++t){
    float4 v = *(const float4*)(base + t*H_ + lane*4);
    adx += v.x; ady += v.y; adz += v.z; adw += v.w;
    float s = v.x*v.x + v.y*v.y + v.z*v.z + v.w*v.w;
    #pragma unroll
    for (int off=32; off; off>>=1) s += __shfl_xor(s, off);
    lacc += sqrtf(s);
  }
  const float inv = 1.f/(float)(T_-1);
  float4 o; o.x=adx*inv; o.y=ady*inv; o.z=adz*inv; o.w=adw*inv;
  *(float4*)(out_ldim + (size_t)b*H_ + lane*4) = o;
  float4 z; z.x=0.f; z.y=0.f; z.z=0.f; z.w=0.f;
  *(float4*)(out_ldt + (size_t)b*(T_*H_) + (size_t)(T_-1)*H_ + lane*4) = z;
  if (lane==0) out_loss[b] = lacc*inv;
}

// ---------------------------------------------------------------------------
extern "C" void kernel_launch(void* const* d_in, const int* in_sizes, int n_in,
                              void* d_out, int out_size, void* d_ws, size_t ws_size,
                              hipStream_t stream){
  const float* x     = (const float*)d_in[0];
  const float* W_enc = (const float*)d_in[1];
  const float* b_enc = (const float*)d_in[2];
  const float* W_ih  = (const float*)d_in[3];
  const float* b_ih  = (const float*)d_in[4];
  const float* W_hh  = (const float*)d_in[5];
  const float* b_hh  = (const float*)d_in[6];

  // workspace layout (requires ~76.3 MB)
  char* ws = (char*)d_ws;
  unsigned short* enc   = (unsigned short*)(ws);                 // 67,108,864 B
  unsigned short* hbuf0 = (unsigned short*)(ws + 67108864);      //  2,097,152 B
  unsigned short* hbuf1 = (unsigned short*)(ws + 69206016);      //  2,097,152 B
  float*          cbuf  = (float*)        (ws + 71303168);       //  4,194,304 B
  unsigned short* Wcat  = (unsigned short*)(ws + 75497472);      //    786,432 B
  float*          biasc = (float*)        (ws + 76283904);       //      4,096 B

  float* out_hn   = (float*)d_out;
  float* out_loss = out_hn  + (size_t)B_*H_;
  float* out_ldim = out_loss + B_;
  float* out_ldt  = out_ldim + (size_t)B_*H_;

  init_kernel<<<4096, 256, 0, stream>>>(W_ih, b_ih, W_hh, b_hh, Wcat, biasc, hbuf0, cbuf);
  enc_kernel<<<2048, 256, 0, stream>>>(x, W_enc, b_enc, enc);
  for (int t=0; t<T_; ++t){
    const unsigned short* hi = (t & 1) ? hbuf1 : hbuf0;
    unsigned short*       ho = (t & 1) ? hbuf0 : hbuf1;
    step_kernel<<<dim3(64,4), 256, 0, stream>>>(enc, Wcat, biasc, hi, ho, cbuf, x,
                                                out_hn, out_ldt, t);
  }
  final_kernel<<<1024, 256, 0, stream>>>(out_loss, out_ldim, out_ldt);
}